// Round 1
// baseline (1207.496 us; speedup 1.0000x reference)
//
#include <hip/hip_runtime.h>
#include <hip/hip_bf16.h>
#include <math.h>

#define T_TOK 8192
#define HID 1024
#define IDIM 4096
#define NE 8
#define TK (T_TOK*2)

typedef __attribute__((ext_vector_type(8))) short short8;
typedef __attribute__((ext_vector_type(4))) float f32x4;

// ---------------- weight fp32 -> bf16 ----------------
__global__ __launch_bounds__(256) void cvt_kernel(const float* __restrict__ src,
                                                  __hip_bfloat16* __restrict__ dst, int n4)
{
    int i = blockIdx.x * 256 + threadIdx.x;
    int stride = gridDim.x * 256;
    for (; i < n4; i += stride) {
        float4 v = ((const float4*)src)[i];
        union { __hip_bfloat16 h[4]; ushort4 u; } t;
        t.h[0] = __float2bfloat16(v.x);
        t.h[1] = __float2bfloat16(v.y);
        t.h[2] = __float2bfloat16(v.z);
        t.h[3] = __float2bfloat16(v.w);
        ((ushort4*)dst)[i] = t.u;
    }
}

// ---------------- router: logits + softmax + top2 ----------------
__global__ __launch_bounds__(64) void router_kernel(const float* __restrict__ x,
                                                    const float* __restrict__ wg,
                                                    float* __restrict__ logits_out,
                                                    int* __restrict__ top_idx,
                                                    float* __restrict__ top_w,
                                                    int* __restrict__ counts)
{
    int t = blockIdx.x;
    int lane = threadIdx.x;
    const float* xr = x + (size_t)t * HID;
    float acc[NE];
#pragma unroll
    for (int e = 0; e < NE; e++) acc[e] = 0.f;
    for (int h = lane; h < HID; h += 64) {
        float xv = xr[h];
#pragma unroll
        for (int e = 0; e < NE; e++) acc[e] += xv * wg[e * HID + h];
    }
#pragma unroll
    for (int e = 0; e < NE; e++)
        for (int off = 32; off > 0; off >>= 1)
            acc[e] += __shfl_down(acc[e], off, 64);
    if (lane == 0) {
        float mx = acc[0];
        for (int e = 1; e < NE; e++) mx = fmaxf(mx, acc[e]);
        float p[NE]; float s = 0.f;
        for (int e = 0; e < NE; e++) { p[e] = expf(acc[e] - mx); s += p[e]; }
        for (int e = 0; e < NE; e++) logits_out[(size_t)t * NE + e] = acc[e];
        // top-2 (first occurrence wins ties, like lax.top_k)
        int i1 = 0;
        for (int e = 1; e < NE; e++) if (p[e] > p[i1]) i1 = e;
        int i2 = -1;
        for (int e = 0; e < NE; e++) { if (e == i1) continue; if (i2 < 0 || p[e] > p[i2]) i2 = e; }
        float w1 = p[i1], w2 = p[i2], sw = w1 + w2;
        top_idx[t * 2] = i1; top_idx[t * 2 + 1] = i2;
        top_w[t * 2] = w1 / sw; top_w[t * 2 + 1] = w2 / sw;
        atomicAdd(&counts[i1], 1);
        atomicAdd(&counts[i2], 1);
    }
}

__global__ void scan_kernel(const int* __restrict__ counts, int* __restrict__ offsets)
{
    if (threadIdx.x == 0) {
        int s = 0;
        for (int e = 0; e < NE; e++) { offsets[e] = s; s += counts[e]; }
        offsets[NE] = s;
    }
}

__global__ __launch_bounds__(256) void scatter_kernel(const int* __restrict__ top_idx,
                                                      const float* __restrict__ top_w,
                                                      const int* __restrict__ offsets,
                                                      int* __restrict__ counts2,
                                                      int* __restrict__ expert_tok,
                                                      float* __restrict__ slot_w,
                                                      int* __restrict__ slot_of)
{
    int t = blockIdx.x * 256 + threadIdx.x;
    if (t >= T_TOK) return;
    for (int k = 0; k < 2; k++) {
        int e = top_idx[t * 2 + k];
        int pos = atomicAdd(&counts2[e], 1);
        int slot = offsets[e] + pos;
        expert_tok[slot] = t;
        slot_w[slot] = top_w[t * 2 + k];
        slot_of[t * 2 + k] = slot;
    }
}

__global__ __launch_bounds__(256) void gather_kernel(const float* __restrict__ x,
                                                     const int* __restrict__ expert_tok,
                                                     __hip_bfloat16* __restrict__ xg)
{
    int slot = blockIdx.x;
    int tok = expert_tok[slot];
    const float* src = x + (size_t)tok * HID;
    __hip_bfloat16* dst = xg + (size_t)slot * HID;
    for (int h = threadIdx.x; h < HID; h += 256)
        dst[h] = __float2bfloat16(src[h]);
}

// ---------------- shared MFMA GEMM mainloop ----------------
// A: [cnt x KDIM] bf16 row-major (clamped rows), B: [128 x KDIM] bf16 row-major (pre-offset to n0)
// 128x128 tile, BK=32, 256 threads = 4 waves in 2x2, each wave 64x64 (4x4 16x16 frags)
#define LDS_STRIDE 40  // 32 + 8 pad (keeps 16B alignment, breaks bank conflicts)

template <int KDIM>
__device__ __forceinline__ void moe_gemm_loop(const __hip_bfloat16* __restrict__ A,
                                              int m0, int cnt,
                                              const __hip_bfloat16* __restrict__ B,
                                              __hip_bfloat16* Alds, __hip_bfloat16* Blds,
                                              f32x4 (&acc)[4][4])
{
    const int tid = threadIdx.x;
    const int lane = tid & 63, wave = tid >> 6;
    const int wm = (wave & 1) * 64, wn = (wave >> 1) * 64;
    const int fm = lane & 15, q = lane >> 4;

    for (int kt = 0; kt < KDIM / 32; ++kt) {
        const int k0 = kt * 32;
        __syncthreads();
#pragma unroll
        for (int i = 0; i < 2; i++) {
            int cid = tid + 256 * i;       // 512 chunks of 16B each per tile
            int r = cid >> 2, c = cid & 3; // row, 16B-chunk within row (8 bf16)
            int ra = m0 + r; ra = (ra < cnt) ? ra : (cnt - 1);
            *(uint4*)&Alds[r * LDS_STRIDE + c * 8] =
                *(const uint4*)&A[(size_t)ra * KDIM + k0 + c * 8];
            *(uint4*)&Blds[r * LDS_STRIDE + c * 8] =
                *(const uint4*)&B[(size_t)r * KDIM + k0 + c * 8];
        }
        __syncthreads();
        short8 af[4], bfr[4];
#pragma unroll
        for (int mi = 0; mi < 4; mi++)
            af[mi] = *(const short8*)&Alds[(wm + mi * 16 + fm) * LDS_STRIDE + q * 8];
#pragma unroll
        for (int ni = 0; ni < 4; ni++)
            bfr[ni] = *(const short8*)&Blds[(wn + ni * 16 + fm) * LDS_STRIDE + q * 8];
#pragma unroll
        for (int mi = 0; mi < 4; mi++)
#pragma unroll
            for (int ni = 0; ni < 4; ni++)
                acc[mi][ni] = __builtin_amdgcn_mfma_f32_16x16x32_bf16(af[mi], bfr[ni],
                                                                      acc[mi][ni], 0, 0, 0);
    }
}

// ---------------- GEMM 1: ht = gelu(Xg @ w_fc^T + b_fc) ----------------
__global__ __launch_bounds__(256) void gemm_fc_kernel(const __hip_bfloat16* __restrict__ xg,
                                                      const __hip_bfloat16* __restrict__ wfc,
                                                      const float* __restrict__ b_fc,
                                                      const int* __restrict__ offsets,
                                                      __hip_bfloat16* __restrict__ ht)
{
    __shared__ __hip_bfloat16 Alds[128 * LDS_STRIDE];
    __shared__ __hip_bfloat16 Blds[128 * LDS_STRIDE];
    const int e = blockIdx.z;
    const int off = offsets[e];
    const int cnt = offsets[e + 1] - off;
    const int m0 = blockIdx.y * 128;
    if (m0 >= cnt) return;
    const int n0 = blockIdx.x * 128;

    f32x4 acc[4][4] = {};
    moe_gemm_loop<HID>(xg + (size_t)off * HID, m0, cnt,
                       wfc + (size_t)e * IDIM * HID + (size_t)n0 * HID, Alds, Blds, acc);

    const int tid = threadIdx.x, lane = tid & 63, wave = tid >> 6;
    const int wm = (wave & 1) * 64, wn = (wave >> 1) * 64, fm = lane & 15, q = lane >> 4;
#pragma unroll
    for (int ni = 0; ni < 4; ni++) {
        int n = n0 + wn + ni * 16 + fm;
        float bias = b_fc[(size_t)e * IDIM + n];
#pragma unroll
        for (int mi = 0; mi < 4; mi++) {
#pragma unroll
            for (int r = 0; r < 4; r++) {
                int m = m0 + wm + mi * 16 + q * 4 + r;
                if (m < cnt) {
                    float v = acc[mi][ni][r] + bias;
                    float g = 0.5f * v * (1.0f + erff(v * 0.70710678118654752f));
                    ht[(size_t)(off + m) * IDIM + n] = __float2bfloat16(g);
                }
            }
        }
    }
}

// ---------------- GEMM 2: contrib = (ht @ w_proj^T + b_proj) * gate_w ----------------
__global__ __launch_bounds__(256) void gemm_proj_kernel(const __hip_bfloat16* __restrict__ ht,
                                                        const __hip_bfloat16* __restrict__ wproj,
                                                        const float* __restrict__ b_proj,
                                                        const int* __restrict__ offsets,
                                                        const float* __restrict__ slot_w,
                                                        __hip_bfloat16* __restrict__ contrib)
{
    __shared__ __hip_bfloat16 Alds[128 * LDS_STRIDE];
    __shared__ __hip_bfloat16 Blds[128 * LDS_STRIDE];
    const int e = blockIdx.z;
    const int off = offsets[e];
    const int cnt = offsets[e + 1] - off;
    const int m0 = blockIdx.y * 128;
    if (m0 >= cnt) return;
    const int n0 = blockIdx.x * 128;

    f32x4 acc[4][4] = {};
    moe_gemm_loop<IDIM>(ht + (size_t)off * IDIM, m0, cnt,
                        wproj + (size_t)e * HID * IDIM + (size_t)n0 * IDIM, Alds, Blds, acc);

    const int tid = threadIdx.x, lane = tid & 63, wave = tid >> 6;
    const int wm = (wave & 1) * 64, wn = (wave >> 1) * 64, fm = lane & 15, q = lane >> 4;
#pragma unroll
    for (int mi = 0; mi < 4; mi++) {
#pragma unroll
        for (int r = 0; r < 4; r++) {
            int m = m0 + wm + mi * 16 + q * 4 + r;
            if (m >= cnt) continue;
            float sw = slot_w[off + m];
#pragma unroll
            for (int ni = 0; ni < 4; ni++) {
                int n = n0 + wn + ni * 16 + fm;
                float v = acc[mi][ni][r] + b_proj[(size_t)e * HID + n];
                contrib[(size_t)(off + m) * HID + n] = __float2bfloat16(v * sw);
            }
        }
    }
}

// ---------------- combine: out[t] = contrib[slot0] + contrib[slot1] ----------------
__global__ __launch_bounds__(256) void combine_kernel(const __hip_bfloat16* __restrict__ contrib,
                                                      const int* __restrict__ slot_of,
                                                      float* __restrict__ out)
{
    int t = blockIdx.x;
    int s0 = slot_of[t * 2], s1 = slot_of[t * 2 + 1];
    const __hip_bfloat16* c0 = contrib + (size_t)s0 * HID;
    const __hip_bfloat16* c1 = contrib + (size_t)s1 * HID;
    float* o = out + (size_t)t * HID;
    for (int h = threadIdx.x; h < HID; h += 256)
        o[h] = __bfloat162float(c0[h]) + __bfloat162float(c1[h]);
}

extern "C" void kernel_launch(void* const* d_in, const int* in_sizes, int n_in,
                              void* d_out, int out_size, void* d_ws, size_t ws_size,
                              hipStream_t stream)
{
    const float* x      = (const float*)d_in[0];
    const float* w_gate = (const float*)d_in[1];
    const float* w_fc   = (const float*)d_in[2];
    const float* b_fc   = (const float*)d_in[3];
    const float* w_proj = (const float*)d_in[4];
    const float* b_proj = (const float*)d_in[5];
    float* out = (float*)d_out;
    float* logits_out = out + (size_t)T_TOK * HID;

    char* ws = (char*)d_ws;
    const size_t WB = (size_t)NE * IDIM * HID * 2;   // one bf16 weight matrix: 64 MiB... (67108864 B)
    size_t o_wfc     = 0;
    size_t o_wproj   = o_wfc + WB;
    size_t o_xg      = o_wproj + WB;
    size_t o_ht      = o_xg + (size_t)TK * HID * 2;
    size_t o_contrib = o_ht + (size_t)TK * IDIM * 2;
    size_t o_route   = o_contrib + (size_t)TK * HID * 2;

    __hip_bfloat16* wfc_b   = (__hip_bfloat16*)(ws + o_wfc);
    __hip_bfloat16* wproj_b = (__hip_bfloat16*)(ws + o_wproj);
    __hip_bfloat16* xg      = (__hip_bfloat16*)(ws + o_xg);
    __hip_bfloat16* ht      = (__hip_bfloat16*)(ws + o_ht);
    __hip_bfloat16* contrib = (__hip_bfloat16*)(ws + o_contrib);

    size_t ro = o_route;
    int*   top_idx    = (int*)(ws + ro);   ro += (size_t)T_TOK * 2 * 4;
    float* top_w      = (float*)(ws + ro); ro += (size_t)T_TOK * 2 * 4;
    int*   counts     = (int*)(ws + ro);   ro += NE * 4;
    int*   counts2    = (int*)(ws + ro);   ro += NE * 4;
    int*   offsets    = (int*)(ws + ro);   ro += 16 * 4;
    int*   expert_tok = (int*)(ws + ro);   ro += (size_t)TK * 4;
    float* slot_w     = (float*)(ws + ro); ro += (size_t)TK * 4;
    int*   slot_of    = (int*)(ws + ro);   ro += (size_t)T_TOK * 2 * 4;

    if (ws_size < ro) return;  // workspace too small — fail visibly

    // zero the two atomic counter arrays (ws is poisoned 0xAA before each launch)
    hipMemsetAsync(counts, 0, 2 * NE * sizeof(int), stream);

    const int n4 = NE * IDIM * HID / 4;
    cvt_kernel<<<2048, 256, 0, stream>>>(w_fc, wfc_b, n4);
    cvt_kernel<<<2048, 256, 0, stream>>>(w_proj, wproj_b, n4);

    router_kernel<<<T_TOK, 64, 0, stream>>>(x, w_gate, logits_out, top_idx, top_w, counts);
    scan_kernel<<<1, 64, 0, stream>>>(counts, offsets);
    scatter_kernel<<<T_TOK / 256, 256, 0, stream>>>(top_idx, top_w, offsets, counts2,
                                                    expert_tok, slot_w, slot_of);
    gather_kernel<<<TK, 256, 0, stream>>>(x, expert_tok, xg);

    gemm_fc_kernel<<<dim3(IDIM / 128, T_TOK / 128, NE), 256, 0, stream>>>(
        xg, wfc_b, b_fc, offsets, ht);
    gemm_proj_kernel<<<dim3(HID / 128, T_TOK / 128, NE), 256, 0, stream>>>(
        ht, wproj_b, b_proj, offsets, slot_w, contrib);

    combine_kernel<<<T_TOK, 256, 0, stream>>>(contrib, slot_of, out);
}

// Round 2
// 1135.892 us; speedup vs baseline: 1.0630x; 1.0630x over previous
//
#include <hip/hip_runtime.h>
#include <hip/hip_bf16.h>
#include <math.h>

#define T_TOK 8192
#define HID 1024
#define IDIM 4096
#define NE 8
#define TK (T_TOK*2)

typedef __attribute__((ext_vector_type(8))) short short8;
typedef __attribute__((ext_vector_type(4))) float f32x4;

// async global -> LDS, 16B per lane. LDS dest = wave-uniform base + lane*16.
__device__ __forceinline__ void gld_lds16(const __hip_bfloat16* g, __hip_bfloat16* l)
{
    __builtin_amdgcn_global_load_lds(
        (const __attribute__((address_space(1))) void*)g,
        (__attribute__((address_space(3))) void*)l, 16, 0, 0);
}

// ---------------- weight fp32 -> bf16 ----------------
__global__ __launch_bounds__(256) void cvt_kernel(const float* __restrict__ src,
                                                  __hip_bfloat16* __restrict__ dst, int n4)
{
    int i = blockIdx.x * 256 + threadIdx.x;
    int stride = gridDim.x * 256;
    for (; i < n4; i += stride) {
        float4 v = ((const float4*)src)[i];
        union { __hip_bfloat16 h[4]; ushort4 u; } t;
        t.h[0] = __float2bfloat16(v.x);
        t.h[1] = __float2bfloat16(v.y);
        t.h[2] = __float2bfloat16(v.z);
        t.h[3] = __float2bfloat16(v.w);
        ((ushort4*)dst)[i] = t.u;
    }
}

// ---------------- router: logits + softmax + top2 ----------------
__global__ __launch_bounds__(64) void router_kernel(const float* __restrict__ x,
                                                    const float* __restrict__ wg,
                                                    float* __restrict__ logits_out,
                                                    int* __restrict__ top_idx,
                                                    float* __restrict__ top_w,
                                                    int* __restrict__ counts)
{
    int t = blockIdx.x;
    int lane = threadIdx.x;
    const float* xr = x + (size_t)t * HID;
    float acc[NE];
#pragma unroll
    for (int e = 0; e < NE; e++) acc[e] = 0.f;
    for (int h = lane; h < HID; h += 64) {
        float xv = xr[h];
#pragma unroll
        for (int e = 0; e < NE; e++) acc[e] += xv * wg[e * HID + h];
    }
#pragma unroll
    for (int e = 0; e < NE; e++)
        for (int off = 32; off > 0; off >>= 1)
            acc[e] += __shfl_down(acc[e], off, 64);
    if (lane == 0) {
        float mx = acc[0];
        for (int e = 1; e < NE; e++) mx = fmaxf(mx, acc[e]);
        float p[NE]; float s = 0.f;
        for (int e = 0; e < NE; e++) { p[e] = expf(acc[e] - mx); s += p[e]; }
        for (int e = 0; e < NE; e++) logits_out[(size_t)t * NE + e] = acc[e];
        int i1 = 0;
        for (int e = 1; e < NE; e++) if (p[e] > p[i1]) i1 = e;
        int i2 = -1;
        for (int e = 0; e < NE; e++) { if (e == i1) continue; if (i2 < 0 || p[e] > p[i2]) i2 = e; }
        float w1 = p[i1], w2 = p[i2], sw = w1 + w2;
        top_idx[t * 2] = i1; top_idx[t * 2 + 1] = i2;
        top_w[t * 2] = w1 / sw; top_w[t * 2 + 1] = w2 / sw;
        atomicAdd(&counts[i1], 1);
        atomicAdd(&counts[i2], 1);
    }
}

__global__ void scan_kernel(const int* __restrict__ counts, int* __restrict__ offsets)
{
    if (threadIdx.x == 0) {
        int s = 0;
        for (int e = 0; e < NE; e++) { offsets[e] = s; s += counts[e]; }
        offsets[NE] = s;
    }
}

__global__ __launch_bounds__(256) void scatter_kernel(const int* __restrict__ top_idx,
                                                      const float* __restrict__ top_w,
                                                      const int* __restrict__ offsets,
                                                      int* __restrict__ counts2,
                                                      int* __restrict__ expert_tok,
                                                      float* __restrict__ slot_w,
                                                      int* __restrict__ slot_of)
{
    int t = blockIdx.x * 256 + threadIdx.x;
    if (t >= T_TOK) return;
    for (int k = 0; k < 2; k++) {
        int e = top_idx[t * 2 + k];
        int pos = atomicAdd(&counts2[e], 1);
        int slot = offsets[e] + pos;
        expert_tok[slot] = t;
        slot_w[slot] = top_w[t * 2 + k];
        slot_of[t * 2 + k] = slot;
    }
}

// gather x rows -> bf16, vectorized: 256 threads x 4 elements = 1024
__global__ __launch_bounds__(256) void gather_kernel(const float* __restrict__ x,
                                                     const int* __restrict__ expert_tok,
                                                     __hip_bfloat16* __restrict__ xg)
{
    int slot = blockIdx.x;
    int tok = expert_tok[slot];
    const float4* src = (const float4*)(x + (size_t)tok * HID);
    ushort4* dst = (ushort4*)(xg + (size_t)slot * HID);
    int h = threadIdx.x;
    float4 v = src[h];
    union { __hip_bfloat16 h4[4]; ushort4 u; } t;
    t.h4[0] = __float2bfloat16(v.x);
    t.h4[1] = __float2bfloat16(v.y);
    t.h4[2] = __float2bfloat16(v.z);
    t.h4[3] = __float2bfloat16(v.w);
    dst[h] = t.u;
}

// ---------------- shared MFMA GEMM mainloop (m97-style async staging) ----------------
// A: [cnt x KDIM] bf16 row-major (rows clamped), B: [128 x KDIM] bf16 row-major (pre-offset)
// 128x128 tile, BK=32, 256 threads = 4 waves (2x2), each wave 64x64 = 4x4 16x16x32 frags.
// LDS tiles 128x32 bf16, UNPADDED 64B row stride (required by global_load_lds lane layout):
// wave w stages A rows [w*32, w*32+32) via 2 instrs; lane l -> row l>>2, 16B chunk l&3.
template <int KDIM>
__device__ __forceinline__ void moe_gemm_loop(const __hip_bfloat16* __restrict__ A,
                                              int m0, int cnt,
                                              const __hip_bfloat16* __restrict__ B,
                                              __hip_bfloat16* Alds, __hip_bfloat16* Blds,
                                              f32x4 (&acc)[4][4])
{
    const int tid = threadIdx.x;
    const int lane = tid & 63, wave = tid >> 6;
    const int wm = (wave & 1) * 64, wn = (wave >> 1) * 64;
    const int fm = lane & 15, q = lane >> 4;

    // loop-invariant staging addresses
    const int srow = wave * 32 + (lane >> 2);
    const int schunk = (lane & 3) * 8;           // element offset of 16B chunk in row
    int ra0 = m0 + srow;      ra0 = (ra0 < cnt) ? ra0 : (cnt - 1);
    int ra1 = m0 + srow + 16; ra1 = (ra1 < cnt) ? ra1 : (cnt - 1);
    const __hip_bfloat16* gA0 = A + (size_t)ra0 * KDIM + schunk;
    const __hip_bfloat16* gA1 = A + (size_t)ra1 * KDIM + schunk;
    const __hip_bfloat16* gB0 = B + (size_t)srow * KDIM + schunk;
    const __hip_bfloat16* gB1 = B + (size_t)(srow + 16) * KDIM + schunk;
    __hip_bfloat16* lA0 = Alds + (wave * 32) * 32;        // wave-uniform LDS bases
    __hip_bfloat16* lA1 = Alds + (wave * 32 + 16) * 32;
    __hip_bfloat16* lB0 = Blds + (wave * 32) * 32;
    __hip_bfloat16* lB1 = Blds + (wave * 32 + 16) * 32;

    for (int kt = 0; kt < KDIM / 32; ++kt) {
        __syncthreads();                         // LDS consumers of prev iter done
        gld_lds16(gA0, lA0);
        gld_lds16(gA1, lA1);
        gld_lds16(gB0, lB0);
        gld_lds16(gB1, lB1);
        gA0 += 32; gA1 += 32; gB0 += 32; gB1 += 32;
        __syncthreads();                         // staging drained (vmcnt before barrier)

        short8 af[4], bfr[4];
#pragma unroll
        for (int mi = 0; mi < 4; mi++)
            af[mi] = *(const short8*)&Alds[(wm + mi * 16 + fm) * 32 + q * 8];
#pragma unroll
        for (int ni = 0; ni < 4; ni++)
            bfr[ni] = *(const short8*)&Blds[(wn + ni * 16 + fm) * 32 + q * 8];
#pragma unroll
        for (int mi = 0; mi < 4; mi++)
#pragma unroll
            for (int ni = 0; ni < 4; ni++)
                acc[mi][ni] = __builtin_amdgcn_mfma_f32_16x16x32_bf16(af[mi], bfr[ni],
                                                                      acc[mi][ni], 0, 0, 0);
    }
}

// ---------------- GEMM 1: ht = gelu(Xg @ w_fc^T + b_fc) ----------------
__global__ __launch_bounds__(256) void gemm_fc_kernel(const __hip_bfloat16* __restrict__ xg,
                                                      const __hip_bfloat16* __restrict__ wfc,
                                                      const float* __restrict__ b_fc,
                                                      const int* __restrict__ offsets,
                                                      __hip_bfloat16* __restrict__ ht)
{
    __shared__ __hip_bfloat16 Alds[128 * 32];
    __shared__ __hip_bfloat16 Blds[128 * 32];
    const int e = blockIdx.z;
    const int off = offsets[e];
    const int cnt = offsets[e + 1] - off;
    const int m0 = blockIdx.y * 128;
    if (m0 >= cnt) return;
    const int n0 = blockIdx.x * 128;

    f32x4 acc[4][4] = {};
    moe_gemm_loop<HID>(xg + (size_t)off * HID, m0, cnt,
                       wfc + (size_t)e * IDIM * HID + (size_t)n0 * HID, Alds, Blds, acc);

    const int tid = threadIdx.x, lane = tid & 63, wave = tid >> 6;
    const int wm = (wave & 1) * 64, wn = (wave >> 1) * 64, fm = lane & 15, q = lane >> 4;
#pragma unroll
    for (int ni = 0; ni < 4; ni++) {
        int n = n0 + wn + ni * 16 + fm;
        float bias = b_fc[(size_t)e * IDIM + n];
#pragma unroll
        for (int mi = 0; mi < 4; mi++) {
#pragma unroll
            for (int r = 0; r < 4; r++) {
                int m = m0 + wm + mi * 16 + q * 4 + r;
                if (m < cnt) {
                    float v = acc[mi][ni][r] + bias;
                    float g = 0.5f * v * (1.0f + erff(v * 0.70710678118654752f));
                    ht[(size_t)(off + m) * IDIM + n] = __float2bfloat16(g);
                }
            }
        }
    }
}

// ---------------- GEMM 2: contrib = (ht @ w_proj^T + b_proj) * gate_w ----------------
__global__ __launch_bounds__(256) void gemm_proj_kernel(const __hip_bfloat16* __restrict__ ht,
                                                        const __hip_bfloat16* __restrict__ wproj,
                                                        const float* __restrict__ b_proj,
                                                        const int* __restrict__ offsets,
                                                        const float* __restrict__ slot_w,
                                                        __hip_bfloat16* __restrict__ contrib)
{
    __shared__ __hip_bfloat16 Alds[128 * 32];
    __shared__ __hip_bfloat16 Blds[128 * 32];
    const int e = blockIdx.z;
    const int off = offsets[e];
    const int cnt = offsets[e + 1] - off;
    const int m0 = blockIdx.y * 128;
    if (m0 >= cnt) return;
    const int n0 = blockIdx.x * 128;

    f32x4 acc[4][4] = {};
    moe_gemm_loop<IDIM>(ht + (size_t)off * IDIM, m0, cnt,
                        wproj + (size_t)e * HID * IDIM + (size_t)n0 * IDIM, Alds, Blds, acc);

    const int tid = threadIdx.x, lane = tid & 63, wave = tid >> 6;
    const int wm = (wave & 1) * 64, wn = (wave >> 1) * 64, fm = lane & 15, q = lane >> 4;
#pragma unroll
    for (int mi = 0; mi < 4; mi++) {
#pragma unroll
        for (int r = 0; r < 4; r++) {
            int m = m0 + wm + mi * 16 + q * 4 + r;
            if (m >= cnt) continue;
            float sw = slot_w[off + m];
#pragma unroll
            for (int ni = 0; ni < 4; ni++) {
                int n = n0 + wn + ni * 16 + fm;
                float v = acc[mi][ni][r] + b_proj[(size_t)e * HID + n];
                contrib[(size_t)(off + m) * HID + n] = __float2bfloat16(v * sw);
            }
        }
    }
}

// ---------------- combine: out[t] = contrib[slot0] + contrib[slot1] ----------------
__global__ __launch_bounds__(256) void combine_kernel(const __hip_bfloat16* __restrict__ contrib,
                                                      const int* __restrict__ slot_of,
                                                      float* __restrict__ out)
{
    int t = blockIdx.x;
    int s0 = slot_of[t * 2], s1 = slot_of[t * 2 + 1];
    const ushort4* c0 = (const ushort4*)(contrib + (size_t)s0 * HID);
    const ushort4* c1 = (const ushort4*)(contrib + (size_t)s1 * HID);
    float4* o = (float4*)(out + (size_t)t * HID);
    int h = threadIdx.x;
    ushort4 a = c0[h], b = c1[h];
    union { unsigned u; float f; } f0, f1, f2, f3;
    f0.u = ((unsigned)a.x << 16); f1.u = ((unsigned)a.y << 16);
    f2.u = ((unsigned)a.z << 16); f3.u = ((unsigned)a.w << 16);
    union { unsigned u; float f; } g0, g1, g2, g3;
    g0.u = ((unsigned)b.x << 16); g1.u = ((unsigned)b.y << 16);
    g2.u = ((unsigned)b.z << 16); g3.u = ((unsigned)b.w << 16);
    float4 r;
    r.x = f0.f + g0.f; r.y = f1.f + g1.f; r.z = f2.f + g2.f; r.w = f3.f + g3.f;
    o[h] = r;
}

extern "C" void kernel_launch(void* const* d_in, const int* in_sizes, int n_in,
                              void* d_out, int out_size, void* d_ws, size_t ws_size,
                              hipStream_t stream)
{
    const float* x      = (const float*)d_in[0];
    const float* w_gate = (const float*)d_in[1];
    const float* w_fc   = (const float*)d_in[2];
    const float* b_fc   = (const float*)d_in[3];
    const float* w_proj = (const float*)d_in[4];
    const float* b_proj = (const float*)d_in[5];
    float* out = (float*)d_out;
    float* logits_out = out + (size_t)T_TOK * HID;

    char* ws = (char*)d_ws;
    const size_t WB = (size_t)NE * IDIM * HID * 2;   // one bf16 weight tensor = 64 MiB
    size_t o_wfc     = 0;
    size_t o_wproj   = o_wfc + WB;
    size_t o_xg      = o_wproj + WB;
    size_t o_ht      = o_xg + (size_t)TK * HID * 2;
    size_t o_contrib = o_ht + (size_t)TK * IDIM * 2;
    size_t o_route   = o_contrib + (size_t)TK * HID * 2;

    __hip_bfloat16* wfc_b   = (__hip_bfloat16*)(ws + o_wfc);
    __hip_bfloat16* wproj_b = (__hip_bfloat16*)(ws + o_wproj);
    __hip_bfloat16* xg      = (__hip_bfloat16*)(ws + o_xg);
    __hip_bfloat16* ht      = (__hip_bfloat16*)(ws + o_ht);
    __hip_bfloat16* contrib = (__hip_bfloat16*)(ws + o_contrib);

    size_t ro = o_route;
    int*   top_idx    = (int*)(ws + ro);   ro += (size_t)T_TOK * 2 * 4;
    float* top_w      = (float*)(ws + ro); ro += (size_t)T_TOK * 2 * 4;
    int*   counts     = (int*)(ws + ro);   ro += NE * 4;
    int*   counts2    = (int*)(ws + ro);   ro += NE * 4;
    int*   offsets    = (int*)(ws + ro);   ro += 16 * 4;
    int*   expert_tok = (int*)(ws + ro);   ro += (size_t)TK * 4;
    float* slot_w     = (float*)(ws + ro); ro += (size_t)TK * 4;
    int*   slot_of    = (int*)(ws + ro);   ro += (size_t)T_TOK * 2 * 4;

    if (ws_size < ro) return;

    hipMemsetAsync(counts, 0, 2 * NE * sizeof(int), stream);

    const int n4 = NE * IDIM * HID / 4;
    cvt_kernel<<<2048, 256, 0, stream>>>(w_fc, wfc_b, n4);
    cvt_kernel<<<2048, 256, 0, stream>>>(w_proj, wproj_b, n4);

    router_kernel<<<T_TOK, 64, 0, stream>>>(x, w_gate, logits_out, top_idx, top_w, counts);
    scan_kernel<<<1, 64, 0, stream>>>(counts, offsets);
    scatter_kernel<<<T_TOK / 256, 256, 0, stream>>>(top_idx, top_w, offsets, counts2,
                                                    expert_tok, slot_w, slot_of);
    gather_kernel<<<TK, 256, 0, stream>>>(x, expert_tok, xg);

    gemm_fc_kernel<<<dim3(IDIM / 128, T_TOK / 128, NE), 256, 0, stream>>>(
        xg, wfc_b, b_fc, offsets, ht);
    gemm_proj_kernel<<<dim3(HID / 128, T_TOK / 128, NE), 256, 0, stream>>>(
        ht, wproj_b, b_proj, offsets, slot_w, contrib);

    combine_kernel<<<T_TOK, 256, 0, stream>>>(contrib, slot_of, out);
}